// Round 1
// baseline (233.173 us; speedup 1.0000x reference)
//
#include <hip/hip_runtime.h>
#include <hip/hip_fp16.h>
#include <cstdint>

#define BB 2
#define SS 512
#define EE 256
#define NN (BB*SS)          // 1024 rows (b*S+i)
#define KTOT (EE*EE)        // 65536
#define SPLITK 32
#define KCHUNK (KTOT/SPLITK) // 2048
#define LN_EPS 1e-3f

typedef _Float16 f16;
typedef _Float16 f16x8 __attribute__((ext_vector_type(8)));
typedef _Float16 f16x4 __attribute__((ext_vector_type(4)));
typedef float    f32x4 __attribute__((ext_vector_type(4)));

// ---------------- Kernel 1: weighted prefix sum s[n,e] = sum_{j<i} x[b,j,e]/(i-j)^2
__global__ void prefix_kernel(const float* __restrict__ x, float* __restrict__ s) {
    __shared__ float wl[SS];
    for (int d = threadIdx.x; d < SS; d += 256)
        wl[d] = (d > 0) ? (1.0f / ((float)d * (float)d)) : 0.0f;
    __syncthreads();
    const int n = blockIdx.x;
    const int b = n >> 9, i = n & (SS - 1);
    const int e = threadIdx.x;
    const float* xb = x + ((size_t)b * SS) * EE + e;
    float acc = 0.0f;
    #pragma unroll 4
    for (int j = 0; j < i; ++j)
        acc += xb[(size_t)j * EE] * wl[i - j];
    s[(size_t)n * EE + e] = acc;
}

// ---------------- Kernel 2: concept_map fp32 -> f16
__global__ void cvt_kernel(const float* __restrict__ cm, f16* __restrict__ cm16) {
    const size_t idx = ((size_t)blockIdx.x * 256 + threadIdx.x) * 4;
    float4 v = *(const float4*)(cm + idx);
    f16x4 h = { (f16)v.x, (f16)v.y, (f16)v.z, (f16)v.w };
    *(f16x4*)(cm16 + idx) = h;
}

// ---------------- Kernel 3: split-K MFMA GEMM
// out_partial[chunk][n][c] = sum_{k in chunk} V[n,k]*CM[c,k],
// V[n, a*256+p] = x[n,a]*s[n,p] generated on the fly.
// WG: 256 threads = 4 waves (2 row-groups x 2 col-groups). Tile: 64 n x 256 c.
__launch_bounds__(256, 2)
__global__ void gemm_kernel(const float* __restrict__ x,
                            const float* __restrict__ sbuf,
                            const f16* __restrict__ cm16,
                            float* __restrict__ part) {
    // LDS B-tile: [buf][slot(k-octet) 0..3][c 0..255][8 f16] ; 2 x 16KB
    __shared__ __align__(16) f16 Bs[2][4 * EE * 8];
    const int tid  = threadIdx.x;
    const int lane = tid & 63;
    const int wave = tid >> 6;
    const int wrow = wave >> 1;       // 0..1 -> +32 rows
    const int wcol = wave & 1;        // 0..1 -> +128 cols
    const int nblock = blockIdx.x;
    const int chunk  = blockIdx.y;
    const int kbase  = chunk * KCHUNK;

    f32x4 acc[2][8];
    #pragma unroll
    for (int a = 0; a < 2; ++a)
        #pragma unroll
        for (int b = 0; b < 8; ++b) acc[a][b] = (f32x4){0.f, 0.f, 0.f, 0.f};

    auto stage = [&](int buf, int st) {
        const int kk = kbase + st * 32;
        const f16* src = cm16 + (size_t)tid * KTOT + kk;  // row c=tid, 32 k's = 64B
        #pragma unroll
        for (int slot = 0; slot < 4; ++slot) {
            f16x8 v = *(const f16x8*)(src + slot * 8);
            *(f16x8*)(&Bs[buf][slot * 2048 + tid * 8]) = v;
        }
    };

    stage(0, 0);

    const int r0    = nblock * 64 + wrow * 32 + (lane & 15);
    const int kgrp  = lane >> 4;             // k-octet 0..3
    const int cbase = wcol * 128 + (lane & 15);
    const int NSTEP = KCHUNK / 32;           // 64

    for (int st = 0; st < NSTEP; ++st) {
        __syncthreads();
        if (st + 1 < NSTEP) stage((st + 1) & 1, st + 1);
        const int cur = st & 1;
        const int kk  = kbase + st * 32;
        const int a_idx = kk >> 8;                 // 'a' index (fixed across the 32-k step)
        const int p0    = (kk & 255) + kgrp * 8;   // 'p' base for this lane's octet

        // A fragments: V[r, kk + kgrp*8 + i] = x[r,a] * s[r, p0+i]
        f16x8 af[2];
        #pragma unroll
        for (int rt = 0; rt < 2; ++rt) {
            const int r = r0 + rt * 16;
            const float xv = x[(size_t)r * EE + a_idx];
            float4 s0 = *(const float4*)(sbuf + (size_t)r * EE + p0);
            float4 s1 = *(const float4*)(sbuf + (size_t)r * EE + p0 + 4);
            af[rt][0] = (f16)(xv * s0.x);
            af[rt][1] = (f16)(xv * s0.y);
            af[rt][2] = (f16)(xv * s0.z);
            af[rt][3] = (f16)(xv * s0.w);
            af[rt][4] = (f16)(xv * s1.x);
            af[rt][5] = (f16)(xv * s1.y);
            af[rt][6] = (f16)(xv * s1.z);
            af[rt][7] = (f16)(xv * s1.w);
        }

        const f16* bbase = &Bs[cur][kgrp * 2048 + cbase * 8];
        #pragma unroll
        for (int ct = 0; ct < 8; ++ct) {
            f16x8 bf = *(const f16x8*)(bbase + ct * 128);
            acc[0][ct] = __builtin_amdgcn_mfma_f32_16x16x32_f16(af[0], bf, acc[0][ct], 0, 0, 0);
            acc[1][ct] = __builtin_amdgcn_mfma_f32_16x16x32_f16(af[1], bf, acc[1][ct], 0, 0, 0);
        }
    }

    // Epilogue: C/D layout col = lane&15, row = (lane>>4)*4 + reg
    const int rrow = (lane >> 4) * 4;
    #pragma unroll
    for (int rt = 0; rt < 2; ++rt) {
        #pragma unroll
        for (int ct = 0; ct < 8; ++ct) {
            const int c  = wcol * 128 + ct * 16 + (lane & 15);
            const int rb = nblock * 64 + wrow * 32 + rt * 16 + rrow;
            #pragma unroll
            for (int q = 0; q < 4; ++q)
                part[((size_t)chunk * NN + rb + q) * EE + c] = acc[rt][ct][q];
        }
    }
}

// ---------------- Kernel 4: split-K reduce + residual + LayerNorm
__global__ void reduce_ln_kernel(const float* __restrict__ x,
                                 const float* __restrict__ part,
                                 const float* __restrict__ gamma,
                                 const float* __restrict__ beta,
                                 float* __restrict__ out) {
    const int n = blockIdx.x;
    const int c = threadIdx.x;
    const int lane = c & 63, wave = c >> 6;
    float y = x[(size_t)n * EE + c];
    #pragma unroll 8
    for (int ch = 0; ch < SPLITK; ++ch)
        y += part[((size_t)ch * NN + n) * EE + c];

    float v = y;
    #pragma unroll
    for (int o = 32; o > 0; o >>= 1) v += __shfl_xor(v, o);
    __shared__ float red[8];
    if (lane == 0) red[wave] = v;
    __syncthreads();
    const float mean = (red[0] + red[1] + red[2] + red[3]) * (1.0f / EE);
    const float d = y - mean;
    float sq = d * d;
    #pragma unroll
    for (int o = 32; o > 0; o >>= 1) sq += __shfl_xor(sq, o);
    if (lane == 0) red[4 + wave] = sq;
    __syncthreads();
    const float var = (red[4] + red[5] + red[6] + red[7]) * (1.0f / EE);
    out[(size_t)n * EE + c] = d * rsqrtf(var + LN_EPS) * gamma[c] + beta[c];
}

extern "C" void kernel_launch(void* const* d_in, const int* in_sizes, int n_in,
                              void* d_out, int out_size, void* d_ws, size_t ws_size,
                              hipStream_t stream) {
    const float* x     = (const float*)d_in[0];
    const float* cm    = (const float*)d_in[1];
    const float* gamma = (const float*)d_in[2];
    const float* beta  = (const float*)d_in[3];
    float* out = (float*)d_out;

    float* sbuf = (float*)d_ws;                                   // NN*EE f32 (1 MB)
    f16*   cm16 = (f16*)(sbuf + (size_t)NN * EE);                 // E^3 f16 (33.5 MB)
    float* part = (float*)((char*)cm16 + (size_t)EE * EE * EE * sizeof(f16)); // 33.5 MB

    hipLaunchKernelGGL(prefix_kernel, dim3(NN), dim3(256), 0, stream, x, sbuf);
    hipLaunchKernelGGL(cvt_kernel, dim3((EE * EE * EE) / (256 * 4)), dim3(256), 0, stream,
                       cm, cm16);
    hipLaunchKernelGGL(gemm_kernel, dim3(NN / 64, SPLITK), dim3(256), 0, stream,
                       x, sbuf, cm16, part);
    hipLaunchKernelGGL(reduce_ln_kernel, dim3(NN), dim3(256), 0, stream,
                       x, part, gamma, beta, out);
}

// Round 2
// 114.263 us; speedup vs baseline: 2.0407x; 2.0407x over previous
//
#include <hip/hip_runtime.h>
#include <hip/hip_fp16.h>
#include <cstdint>

#define BB 2
#define SS 512
#define EE 256
#define NN (BB*SS)           // 1024 rows
#define KTOT (EE*EE)         // 65536
#define SPLITK 32
#define KCHUNK (KTOT/SPLITK) // 2048
#define NSTEP (KCHUNK/32)    // 64 k-steps per chunk
#define TSTEPS (KTOT/32)     // 2048 total k-steps
#define LN_EPS 1e-3f

typedef _Float16 f16;
typedef _Float16 f16x8 __attribute__((ext_vector_type(8)));
typedef float    f32x4 __attribute__((ext_vector_type(4)));

// ---------------- Kernel 1: weighted prefix sum s[n,e] = sum_{j<i} x[b,j,e]/(i-j)^2
__global__ void prefix_kernel(const float* __restrict__ x, float* __restrict__ s) {
    __shared__ float wl[SS];
    for (int d = threadIdx.x; d < SS; d += 256)
        wl[d] = (d > 0) ? (1.0f / ((float)d * (float)d)) : 0.0f;
    __syncthreads();
    const int n = blockIdx.x;
    const int b = n >> 9, i = n & (SS - 1);
    const int e = threadIdx.x;
    const float* xb = x + ((size_t)b * SS) * EE + e;
    float acc = 0.0f;
    #pragma unroll 4
    for (int j = 0; j < i; ++j)
        acc += xb[(size_t)j * EE] * wl[i - j];
    s[(size_t)n * EE + e] = acc;
}

// ---------------- Kernel 2: pack/transpose cm f32 -> cmP f16 in GEMM staging order.
// Block t (0..2047) covers k in [t*32, t*32+32). Block layout (8192 f16 = 16 KB):
//   idx = slot*2048 + c*8 + j   ->  cm[c][t*32 + slot*8 + j]
__global__ void pack_kernel(const float* __restrict__ cm, f16* __restrict__ cmP) {
    const int t    = blockIdx.x;
    const int tid  = threadIdx.x;        // 256 threads
    const int slot = tid >> 6;           // 0..3 (= wave)
    const int cq   = (tid & 63) * 4;     // c base for this thread
    const float* src = cm + (size_t)t * 32 + slot * 8;
    f16* dst = cmP + (size_t)t * 8192 + tid * 32;
    #pragma unroll
    for (int u = 0; u < 4; ++u) {
        const float* row = src + (size_t)(cq + u) * KTOT;
        float4 lo = *(const float4*)(row);
        float4 hi = *(const float4*)(row + 4);
        f16x8 h = { (f16)lo.x, (f16)lo.y, (f16)lo.z, (f16)lo.w,
                    (f16)hi.x, (f16)hi.y, (f16)hi.z, (f16)hi.w };
        *(f16x8*)(dst + u * 8) = h;
    }
}

// ---------------- Kernel 3: split-K MFMA GEMM
// out_partial[chunk][n][c] = sum_{k in chunk} V[n,k]*CM[c,k],
// V[n, a*256+p] = x[n,a]*s[n,p] — A built from registers; B streamed
// via global_load_lds from the packed cmP.
__launch_bounds__(256, 2)
__global__ void gemm_kernel(const float* __restrict__ x,
                            const float* __restrict__ sbuf,
                            const f16* __restrict__ cmP,
                            float* __restrict__ part) {
    __shared__ __align__(16) f16 Bs[2][8192];   // 2 x 16 KB
    const int tid  = threadIdx.x;
    const int lane = tid & 63;
    const int wave = tid >> 6;
    const int wrow = wave >> 1;
    const int wcol = wave & 1;

    // XCD-aware swizzle: chunk c's 16 nblocks land on one XCD (4 chunks/XCD).
    const int d = blockIdx.x;            // 0..511
    const int nblock = (d >> 3) & 15;
    const int chunk  = (d & 7) * 4 + (d >> 7);

    const int kgrp  = lane >> 4;
    const int r0    = nblock * 64 + wrow * 32 + (lane & 15);
    const int cbase = wcol * 128 + (lane & 15);

    // ---- A preload: x (8 f16) and s (64 f16) per row-tile, all in registers.
    f16x8 xf[2]; f16x8 sv[2][8];
    #pragma unroll
    for (int rt = 0; rt < 2; ++rt) {
        const int r = r0 + rt * 16;
        const float* xr = x + (size_t)r * EE + chunk * 8;
        #pragma unroll
        for (int a = 0; a < 8; ++a) xf[rt][a] = (f16)xr[a];
        const float* sr = sbuf + (size_t)r * EE + kgrp * 8;
        #pragma unroll
        for (int m = 0; m < 8; ++m) {
            float4 lo = *(const float4*)(sr + m * 32);
            float4 hi = *(const float4*)(sr + m * 32 + 4);
            sv[rt][m] = (f16x8){ (f16)lo.x, (f16)lo.y, (f16)lo.z, (f16)lo.w,
                                 (f16)hi.x, (f16)hi.y, (f16)hi.z, (f16)hi.w };
        }
    }

    f32x4 acc[2][8];
    #pragma unroll
    for (int a = 0; a < 2; ++a)
        #pragma unroll
        for (int b = 0; b < 8; ++b) acc[a][b] = (f32x4){0.f, 0.f, 0.f, 0.f};

    const char* srcBase = (const char*)cmP + (size_t)(chunk * NSTEP) * 16384;
    auto stage = [&](int buf, int st) {
        const char* g = srcBase + (size_t)st * 16384 + wave * 4096 + lane * 16;
        char* l = (char*)&Bs[buf][0] + wave * 4096;   // wave-uniform LDS base
        #pragma unroll
        for (int i = 0; i < 4; ++i) {
            __builtin_amdgcn_global_load_lds(
                (const __attribute__((address_space(1))) void*)(g + i * 1024),
                (__attribute__((address_space(3))) void*)(l + i * 1024),
                16, 0, 0);
        }
    };

    stage(0, 0);

    #pragma unroll
    for (int a_l = 0; a_l < 8; ++a_l) {
        #pragma unroll
        for (int m = 0; m < 8; ++m) {
            const int st = a_l * 8 + m;
            __syncthreads();                       // drains vmcnt -> buf ready
            if (st + 1 < NSTEP) stage((st + 1) & 1, st + 1);
            const f16* bb = &Bs[st & 1][kgrp * 2048 + cbase * 8];
            const f16 xa0 = xf[0][a_l], xa1 = xf[1][a_l];   // static indices
            f16x8 af0, af1;
            #pragma unroll
            for (int i = 0; i < 8; ++i) {
                af0[i] = xa0 * sv[0][m][i];
                af1[i] = xa1 * sv[1][m][i];
            }
            #pragma unroll
            for (int ct = 0; ct < 8; ++ct) {
                f16x8 bf = *(const f16x8*)(bb + ct * 128);
                acc[0][ct] = __builtin_amdgcn_mfma_f32_16x16x32_f16(af0, bf, acc[0][ct], 0, 0, 0);
                acc[1][ct] = __builtin_amdgcn_mfma_f32_16x16x32_f16(af1, bf, acc[1][ct], 0, 0, 0);
            }
        }
    }

    // Epilogue: C/D layout col = lane&15, row = (lane>>4)*4 + reg
    const int rrow = (lane >> 4) * 4;
    #pragma unroll
    for (int rt = 0; rt < 2; ++rt) {
        #pragma unroll
        for (int ct = 0; ct < 8; ++ct) {
            const int c  = wcol * 128 + ct * 16 + (lane & 15);
            const int rb = nblock * 64 + wrow * 32 + rt * 16 + rrow;
            #pragma unroll
            for (int q = 0; q < 4; ++q)
                part[((size_t)chunk * NN + rb + q) * EE + c] = acc[rt][ct][q];
        }
    }
}

// ---------------- Kernel 4: split-K reduce + residual + LayerNorm
__global__ void reduce_ln_kernel(const float* __restrict__ x,
                                 const float* __restrict__ part,
                                 const float* __restrict__ gamma,
                                 const float* __restrict__ beta,
                                 float* __restrict__ out) {
    const int n = blockIdx.x;
    const int c = threadIdx.x;
    const int lane = c & 63, wave = c >> 6;
    float y = x[(size_t)n * EE + c];
    #pragma unroll 8
    for (int ch = 0; ch < SPLITK; ++ch)
        y += part[((size_t)ch * NN + n) * EE + c];

    float v = y;
    #pragma unroll
    for (int o = 32; o > 0; o >>= 1) v += __shfl_xor(v, o);
    __shared__ float red[8];
    if (lane == 0) red[wave] = v;
    __syncthreads();
    const float mean = (red[0] + red[1] + red[2] + red[3]) * (1.0f / EE);
    const float d = y - mean;
    float sq = d * d;
    #pragma unroll
    for (int o = 32; o > 0; o >>= 1) sq += __shfl_xor(sq, o);
    if (lane == 0) red[4 + wave] = sq;
    __syncthreads();
    const float var = (red[4] + red[5] + red[6] + red[7]) * (1.0f / EE);
    out[(size_t)n * EE + c] = d * rsqrtf(var + LN_EPS) * gamma[c] + beta[c];
}

extern "C" void kernel_launch(void* const* d_in, const int* in_sizes, int n_in,
                              void* d_out, int out_size, void* d_ws, size_t ws_size,
                              hipStream_t stream) {
    const float* x     = (const float*)d_in[0];
    const float* cm    = (const float*)d_in[1];
    const float* gamma = (const float*)d_in[2];
    const float* beta  = (const float*)d_in[3];
    float* out = (float*)d_out;

    float* sbuf = (float*)d_ws;                                    // 1 MB
    f16*   cmP  = (f16*)(sbuf + (size_t)NN * EE);                  // 33.5 MB
    float* part = (float*)((char*)cmP + (size_t)TSTEPS * 8192 * sizeof(f16)); // 33.5 MB

    hipLaunchKernelGGL(prefix_kernel, dim3(NN), dim3(256), 0, stream, x, sbuf);
    hipLaunchKernelGGL(pack_kernel, dim3(TSTEPS), dim3(256), 0, stream, cm, cmP);
    hipLaunchKernelGGL(gemm_kernel, dim3(16 * SPLITK), dim3(256), 0, stream,
                       x, sbuf, cmP, part);
    hipLaunchKernelGGL(reduce_ln_kernel, dim3(NN), dim3(256), 0, stream,
                       x, part, gamma, beta, out);
}

// Round 3
// 91.224 us; speedup vs baseline: 2.5560x; 1.2525x over previous
//
#include <hip/hip_runtime.h>
#include <hip/hip_fp16.h>
#include <cstdint>

#define BB 2
#define SS 512
#define EE 256
#define NN (BB*SS)           // 1024 rows
#define KTOT (EE*EE)         // 65536
#define SPLITK 32
#define KCHUNK (KTOT/SPLITK) // 2048
#define NSTEP (KCHUNK/32)    // 64 k-steps per chunk
#define TSTEPS (KTOT/32)     // 2048 total k-steps
#define LN_EPS 1e-3f

typedef _Float16 f16;
typedef _Float16 f16x8 __attribute__((ext_vector_type(8)));
typedef float    f32x4 __attribute__((ext_vector_type(4)));

// ---------------- Kernel 1a: tiled triangular weighted prefix partials.
// Block = (b, eh, it, jt) with jt <= it. i-tile 64, j-tile 64, e-half 128.
// ps[tile][il][ec] = sum_{j in jtile} x[b,j,eh*128+ec] * w(i-j), w(d<=0)=0.
__global__ void wprefix_kernel(const float* __restrict__ x, float* __restrict__ ps) {
    __shared__ float xt[64][128];
    __shared__ float wl2[576];
    const int id = blockIdx.x;             // 144 blocks
    const int eh = id & 1;
    const int rest = id >> 1;
    const int b = rest / 36;
    const int r = rest % 36;
    int it = 0;
    while ((it + 1) * (it + 2) / 2 <= r) ++it;
    const int jt = r - it * (it + 1) / 2;
    const int tid = threadIdx.x;

    for (int t = tid; t < 576; t += 256) {
        const int d = t - 64;
        wl2[t] = (d > 0) ? 1.0f / ((float)d * (float)d) : 0.0f;
    }
    const int jbase = jt * 64, ibase = it * 64;
    const float* xb = x + ((size_t)b * SS + jbase) * EE + eh * 128;
    #pragma unroll
    for (int p = 0; p < 8; ++p) {
        const int row = p * 8 + (tid >> 5);
        const int col = (tid & 31) * 4;
        *(float4*)&xt[row][col] = *(const float4*)(xb + (size_t)row * EE + col);
    }
    __syncthreads();

    const int g  = tid >> 5;        // i-row group 0..7
    const int ec = (tid & 31) * 4;  // e-col (within half)
    const int irow = ibase + g * 8;
    float4 acc[8];
    #pragma unroll
    for (int m = 0; m < 8; ++m) acc[m] = (float4){0.f, 0.f, 0.f, 0.f};

    for (int jj = 0; jj < 64; ++jj) {
        const float4 xv = *(const float4*)&xt[jj][ec];
        const int wbase = irow - (jbase + jj) + 64;   // in [1,575]
        #pragma unroll
        for (int m = 0; m < 8; ++m) {
            const float w = wl2[wbase + m];           // wave-broadcast
            acc[m].x += xv.x * w;
            acc[m].y += xv.y * w;
            acc[m].z += xv.z * w;
            acc[m].w += xv.w * w;
        }
    }

    float* base = ps + ((size_t)(((b * 2 + eh) * 8 + it) * 8 + jt)) * (64 * 128);
    #pragma unroll
    for (int m = 0; m < 8; ++m)
        *(float4*)(base + (size_t)(g * 8 + m) * 128 + ec) = acc[m];
}

// ---------------- Kernel 1b: fold j-tile partials -> s[n,e]
__global__ void reduce_s_kernel(const float* __restrict__ ps, float* __restrict__ s) {
    const int n = blockIdx.x;         // 1024
    const int e = threadIdx.x;        // 256
    const int b = n >> 9, i = n & (SS - 1);
    const int it = i >> 6, il = i & 63;
    const int eh = e >> 7, ec = e & 127;
    const size_t tbase = (size_t)((b * 2 + eh) * 8 + it) * 8;
    float acc = 0.0f;
    for (int jt = 0; jt <= it; ++jt)
        acc += ps[(tbase + jt) * (64 * 128) + (size_t)il * 128 + ec];
    s[(size_t)n * EE + e] = acc;
}

// ---------------- Kernel 2: pack/transpose cm f32 -> cmP f16 in GEMM staging order.
__global__ void pack_kernel(const float* __restrict__ cm, f16* __restrict__ cmP) {
    const int t    = blockIdx.x;
    const int tid  = threadIdx.x;        // 256 threads
    const int slot = tid >> 6;           // 0..3 (= wave)
    const int cq   = (tid & 63) * 4;     // c base for this thread
    const float* src = cm + (size_t)t * 32 + slot * 8;
    f16* dst = cmP + (size_t)t * 8192 + tid * 32;
    #pragma unroll
    for (int u = 0; u < 4; ++u) {
        const float* row = src + (size_t)(cq + u) * KTOT;
        float4 lo = *(const float4*)(row);
        float4 hi = *(const float4*)(row + 4);
        f16x8 h = { (f16)lo.x, (f16)lo.y, (f16)lo.z, (f16)lo.w,
                    (f16)hi.x, (f16)hi.y, (f16)hi.z, (f16)hi.w };
        *(f16x8*)(dst + u * 8) = h;
    }
}

// ---------------- Kernel 3: split-K MFMA GEMM
__launch_bounds__(256, 2)
__global__ void gemm_kernel(const float* __restrict__ x,
                            const float* __restrict__ sbuf,
                            const f16* __restrict__ cmP,
                            float* __restrict__ part) {
    __shared__ __align__(16) f16 Bs[2][8192];   // 2 x 16 KB
    const int tid  = threadIdx.x;
    const int lane = tid & 63;
    const int wave = tid >> 6;
    const int wrow = wave >> 1;
    const int wcol = wave & 1;

    const int d = blockIdx.x;            // 0..511
    const int nblock = (d >> 3) & 15;
    const int chunk  = (d & 7) * 4 + (d >> 7);

    const int kgrp  = lane >> 4;
    const int r0    = nblock * 64 + wrow * 32 + (lane & 15);
    const int cbase = wcol * 128 + (lane & 15);

    f16x8 xf[2]; f16x8 sv[2][8];
    #pragma unroll
    for (int rt = 0; rt < 2; ++rt) {
        const int r = r0 + rt * 16;
        const float* xr = x + (size_t)r * EE + chunk * 8;
        #pragma unroll
        for (int a = 0; a < 8; ++a) xf[rt][a] = (f16)xr[a];
        const float* sr = sbuf + (size_t)r * EE + kgrp * 8;
        #pragma unroll
        for (int m = 0; m < 8; ++m) {
            float4 lo = *(const float4*)(sr + m * 32);
            float4 hi = *(const float4*)(sr + m * 32 + 4);
            sv[rt][m] = (f16x8){ (f16)lo.x, (f16)lo.y, (f16)lo.z, (f16)lo.w,
                                 (f16)hi.x, (f16)hi.y, (f16)hi.z, (f16)hi.w };
        }
    }

    f32x4 acc[2][8];
    #pragma unroll
    for (int a = 0; a < 2; ++a)
        #pragma unroll
        for (int b = 0; b < 8; ++b) acc[a][b] = (f32x4){0.f, 0.f, 0.f, 0.f};

    const char* srcBase = (const char*)cmP + (size_t)(chunk * NSTEP) * 16384;
    auto stage = [&](int buf, int st) {
        const char* g = srcBase + (size_t)st * 16384 + wave * 4096 + lane * 16;
        char* l = (char*)&Bs[buf][0] + wave * 4096;
        #pragma unroll
        for (int i = 0; i < 4; ++i) {
            __builtin_amdgcn_global_load_lds(
                (const __attribute__((address_space(1))) void*)(g + i * 1024),
                (__attribute__((address_space(3))) void*)(l + i * 1024),
                16, 0, 0);
        }
    };

    stage(0, 0);

    #pragma unroll
    for (int a_l = 0; a_l < 8; ++a_l) {
        #pragma unroll
        for (int m = 0; m < 8; ++m) {
            const int st = a_l * 8 + m;
            __syncthreads();
            if (st + 1 < NSTEP) stage((st + 1) & 1, st + 1);
            const f16* bb = &Bs[st & 1][kgrp * 2048 + cbase * 8];
            const f16 xa0 = xf[0][a_l], xa1 = xf[1][a_l];
            f16x8 af0, af1;
            #pragma unroll
            for (int i = 0; i < 8; ++i) {
                af0[i] = xa0 * sv[0][m][i];
                af1[i] = xa1 * sv[1][m][i];
            }
            #pragma unroll
            for (int ct = 0; ct < 8; ++ct) {
                f16x8 bf = *(const f16x8*)(bb + ct * 128);
                acc[0][ct] = __builtin_amdgcn_mfma_f32_16x16x32_f16(af0, bf, acc[0][ct], 0, 0, 0);
                acc[1][ct] = __builtin_amdgcn_mfma_f32_16x16x32_f16(af1, bf, acc[1][ct], 0, 0, 0);
            }
        }
    }

    const int rrow = (lane >> 4) * 4;
    #pragma unroll
    for (int rt = 0; rt < 2; ++rt) {
        #pragma unroll
        for (int ct = 0; ct < 8; ++ct) {
            const int c  = wcol * 128 + ct * 16 + (lane & 15);
            const int rb = nblock * 64 + wrow * 32 + rt * 16 + rrow;
            #pragma unroll
            for (int q = 0; q < 4; ++q)
                part[((size_t)chunk * NN + rb + q) * EE + c] = acc[rt][ct][q];
        }
    }
}

// ---------------- Kernel 4: split-K reduce + residual + LayerNorm
__global__ void reduce_ln_kernel(const float* __restrict__ x,
                                 const float* __restrict__ part,
                                 const float* __restrict__ gamma,
                                 const float* __restrict__ beta,
                                 float* __restrict__ out) {
    const int n = blockIdx.x;
    const int c = threadIdx.x;
    const int lane = c & 63, wave = c >> 6;
    float y = x[(size_t)n * EE + c];
    #pragma unroll 8
    for (int ch = 0; ch < SPLITK; ++ch)
        y += part[((size_t)ch * NN + n) * EE + c];

    float v = y;
    #pragma unroll
    for (int o = 32; o > 0; o >>= 1) v += __shfl_xor(v, o);
    __shared__ float red[8];
    if (lane == 0) red[wave] = v;
    __syncthreads();
    const float mean = (red[0] + red[1] + red[2] + red[3]) * (1.0f / EE);
    const float d = y - mean;
    float sq = d * d;
    #pragma unroll
    for (int o = 32; o > 0; o >>= 1) sq += __shfl_xor(sq, o);
    if (lane == 0) red[4 + wave] = sq;
    __syncthreads();
    const float var = (red[4] + red[5] + red[6] + red[7]) * (1.0f / EE);
    out[(size_t)n * EE + c] = d * rsqrtf(var + LN_EPS) * gamma[c] + beta[c];
}

extern "C" void kernel_launch(void* const* d_in, const int* in_sizes, int n_in,
                              void* d_out, int out_size, void* d_ws, size_t ws_size,
                              hipStream_t stream) {
    const float* x     = (const float*)d_in[0];
    const float* cm    = (const float*)d_in[1];
    const float* gamma = (const float*)d_in[2];
    const float* beta  = (const float*)d_in[3];
    float* out = (float*)d_out;

    float* sbuf = (float*)d_ws;                                    // 1 MB
    f16*   cmP  = (f16*)(sbuf + (size_t)NN * EE);                  // 33.5 MB
    float* part = (float*)((char*)cmP + (size_t)TSTEPS * 8192 * sizeof(f16)); // 33.5 MB
    float* ps   = part;   // prefix partials (8 MB) alias `part` — consumed
                          // by reduce_s before gemm writes part.

    hipLaunchKernelGGL(wprefix_kernel, dim3(144), dim3(256), 0, stream, x, ps);
    hipLaunchKernelGGL(reduce_s_kernel, dim3(NN), dim3(256), 0, stream, ps, sbuf);
    hipLaunchKernelGGL(pack_kernel, dim3(TSTEPS), dim3(256), 0, stream, cm, cmP);
    hipLaunchKernelGGL(gemm_kernel, dim3(16 * SPLITK), dim3(256), 0, stream,
                       x, sbuf, cmP, part);
    hipLaunchKernelGGL(reduce_ln_kernel, dim3(NN), dim3(256), 0, stream,
                       x, part, gamma, beta, out);
}